// Round 8
// baseline (270.772 us; speedup 1.0000x reference)
//
#include <hip/hip_runtime.h>
#include <math.h>

#define HW 16384
#define CDIM 192
#define C3 144
#define C4 48
#define NB 2
#define NPX 32768   // NB*HW
#define HEADS 6

typedef unsigned short u16;
typedef unsigned int u32;
typedef __attribute__((ext_vector_type(8))) short bf16x8;
typedef __attribute__((ext_vector_type(4))) float f32x4;

__device__ __forceinline__ float bf2f(u16 u) {
    return __uint_as_float(((unsigned int)u) << 16);
}
__device__ __forceinline__ u16 f2bf(float f) {
    unsigned int x = __float_as_uint(f);
    unsigned int r = x + 0x7fffu + ((x >> 16) & 1u);  // RNE
    return (u16)(r >> 16);
}

static inline float* wsf(void* ws, size_t off) { return (float*)((char*)ws + off); }
static inline u16* wsh(void* ws, size_t off) { return (u16*)((char*)ws + off); }

// ---------------- K0: setup = weight bf16 conversion + tiny GEMVs + k_v copy -
__global__ void k_setup(const float* __restrict__ kvv, const float* __restrict__ wkR,
                        const float* __restrict__ wkI, const float* __restrict__ wffk,
                        const float* __restrict__ wqR, const float* __restrict__ wkvI,
                        const float* __restrict__ wpo, const float* __restrict__ wpin,
                        const float* __restrict__ wpout,
                        const float* __restrict__ ln2w, const float* __restrict__ ln2b,
                        u16* __restrict__ wb, float* __restrict__ sm,
                        float* __restrict__ A2, float* __restrict__ B2,
                        float* __restrict__ tail) {
    int t = blockIdx.x * 256 + threadIdx.x;
    if (t < 313344) {
        float v;
        if (t < 30720) {
            int o = t / 160, i = t % 160;
            v = (i < 144) ? wqR[o * 144 + i] : 0.f;
        } else if (t < 55296) {
            int r = t - 30720; int o = r / 64, i = r % 64;
            v = (i < 48) ? wkvI[o * 48 + i] : 0.f;
        } else if (t < 92160) {
            v = wpo[t - 55296];
        } else if (t < 239616) {
            v = wpin[t - 92160];
        } else {
            v = wpout[t - 239616];
        }
        wb[t] = f2bf(v);
    } else if (t < 314112) {
        int r = t - 313344;              // 0..767: modulation GEMVs (stored as val+1)
        if (r < 288) {
            int b = r / 144, o = r % 144;
            const float* v = kvv + b * 256;
            const float* w = wkR + o * 192;
            float s = 0.f;
#pragma unroll 8
            for (int j = 0; j < 192; j++) s += v[j] * w[j];
            sm[r] = s + 1.0f;
        } else if (r < 384) {
            int r2 = r - 288;
            int b = r2 / 48, o = r2 % 48;
            const float* v = kvv + b * 256 + 192;
            const float* w = wkI + o * 64;
            float s = 0.f;
#pragma unroll 8
            for (int j = 0; j < 64; j++) s += v[j] * w[j];
            sm[288 + r2] = s + 1.0f;
        } else {
            int r2 = r - 384;
            int b = r2 / 192, o = r2 % 192;
            const float* v = kvv + b * 256;
            const float* w = wffk + o * 256;
            float s = 0.f;
#pragma unroll 8
            for (int j = 0; j < 256; j++) s += v[j] * w[j];
            float sc = s + 1.0f;
            sm[384 + r2] = sc;
            A2[r2] = ln2w[o] * sc;       // fused LN2 scale
            B2[r2] = ln2b[o] * sc;       // fused LN2 bias
        }
    } else if (t < 314624) {
        int r = t - 314112;
        tail[r] = kvv[r];                // k_v pass-through to output tail
    }
}

// ---------------- K1: LN1 + modulation, single-pass, TRANSPOSED bf16 out -----
__global__ __launch_bounds__(256) void k_ln1(
    const float* __restrict__ xin,
    const float* __restrict__ lnw, const float* __restrict__ lnb,
    const float* __restrict__ sca, const float* __restrict__ scb,
    u16* __restrict__ outA, u16* __restrict__ outB) {
    __shared__ float red[2][16][16][4];
    __shared__ float mu_s[16][4], rstd_s[16][4];
    int t = threadIdx.x;
    int px4 = t & 15, cg = t >> 4;
    int base = blockIdx.x * 64;
    int b = base >> 14;
    int p = (base & 16383) + px4 * 4;
    float vals[12][4];
    float s[4] = {0.f, 0.f, 0.f, 0.f}, s2[4] = {0.f, 0.f, 0.f, 0.f};
#pragma unroll
    for (int j = 0; j < 12; j++) {
        int c = cg * 12 + j;
        size_t off = ((size_t)(b * CDIM + c)) * HW + p;
        float4 f = *(const float4*)(xin + off);
        float v[4] = {f.x, f.y, f.z, f.w};
#pragma unroll
        for (int q = 0; q < 4; q++) {
            vals[j][q] = v[q]; s[q] += v[q]; s2[q] += v[q] * v[q];
        }
    }
#pragma unroll
    for (int q = 0; q < 4; q++) { red[0][cg][px4][q] = s[q]; red[1][cg][px4][q] = s2[q]; }
    __syncthreads();
    if (t < 16) {
        float S[4] = {0.f, 0.f, 0.f, 0.f}, S2[4] = {0.f, 0.f, 0.f, 0.f};
        for (int g2 = 0; g2 < 16; g2++)
#pragma unroll
            for (int q = 0; q < 4; q++) { S[q] += red[0][g2][t][q]; S2[q] += red[1][g2][t][q]; }
#pragma unroll
        for (int q = 0; q < 4; q++) {
            float mu = S[q] * (1.0f / CDIM);
            float var = S2[q] * (1.0f / CDIM) - mu * mu;
            mu_s[t][q] = mu;
            rstd_s[t][q] = rsqrtf(var + 1e-5f);
        }
    }
    __syncthreads();
    float mu[4], rs[4];
#pragma unroll
    for (int q = 0; q < 4; q++) { mu[q] = mu_s[px4][q]; rs[q] = rstd_s[px4][q]; }
    float Ac[12], Bc[12];
#pragma unroll
    for (int j = 0; j < 12; j++) {
        int c = cg * 12 + j;
        float sc = (c < C3) ? sca[b * C3 + c] : scb[b * C4 + (c - C3)];
        Ac[j] = lnw[c] * sc;
        Bc[j] = lnb[c] * sc;
    }
    int isR = (cg < 12);
    size_t row0 = (size_t)b * HW + p;
    u16* basep = isR ? (outA + row0 * 160 + cg * 12)
                     : (outB + row0 * 64 + (cg * 12 - 144));
    int rowlen = isR ? 160 : 64;
#pragma unroll
    for (int q = 0; q < 4; q++) {
        u16 tmp[12];
#pragma unroll
        for (int j = 0; j < 12; j++)
            tmp[j] = f2bf((vals[j][q] - mu[q]) * rs[q] * Ac[j] + Bc[j]);
        u16* op = basep + q * rowlen;
        ushort4 o0 = {tmp[0], tmp[1], tmp[2], tmp[3]};
        ushort4 o1 = {tmp[4], tmp[5], tmp[6], tmp[7]};
        ushort4 o2 = {tmp[8], tmp[9], tmp[10], tmp[11]};
        *(ushort4*)(op) = o0;
        *(ushort4*)(op + 4) = o1;
        *(ushort4*)(op + 8) = o2;
    }
    if (cg == 0) {   // zero the K-pad columns so garbage never reaches MFMA
        int4 z = {0, 0, 0, 0};
#pragma unroll
        for (int q = 0; q < 4; q++) {
            u16* pr = outA + (row0 + q) * 160 + 144;
            *(int4*)(pr) = z; *(int4*)(pr + 8) = z;
            u16* pi = outB + (row0 + q) * 64 + 48;
            *(int4*)(pi) = z; *(int4*)(pi + 8) = z;
        }
    }
}

// ---------------- K2: conv1x1 GEMM, LDS-staged, all-b128 fragment reads ------
// MODE 0: out bf16 [b][CO][HW].  MODE 1: resid fp32 std, out bf16 [b][HW][192].
template <int NCH, int MODE>
__global__ __launch_bounds__(256) void k_gemm_t(
    const u16* __restrict__ X, const u16* __restrict__ Wb,
    const void* __restrict__ resid, void* __restrict__ outp, int CO) {
    constexpr int CIP = NCH * 32;
    __shared__ __align__(16) u16 Xs[128 * 40];   // [px][32k] pitch 40 u16
    __shared__ __align__(16) u16 Wsh[64 * 40];   // [m][32k]  pitch 40 u16
    const int tid = threadIdx.x;
    const int n0 = blockIdx.x * 128;
    const int m0 = blockIdx.y * 64;
    const int b = blockIdx.z;
    const int wave = tid >> 6, lane = tid & 63;
    const int quad = lane >> 4, l16 = lane & 15;
    const int spx = tid >> 1, sh = tid & 1;    // X stage: px, k-half(16 u16)
    const int swr = tid >> 2, swc = tid & 3;   // W stage: m-row, k-chunk(8 u16)
    const u16* xsrc = X + ((size_t)b * HW + n0 + spx) * CIP + sh * 16;
    const u16* wsrc = Wb + (size_t)(m0 + swr) * CIP + swc * 8;
    int4 xr0 = *(const int4*)(xsrc);
    int4 xr1 = *(const int4*)(xsrc + 8);
    int4 wr0 = *(const int4*)(wsrc);
    f32x4 acc[4][2] = {};
#pragma unroll
    for (int ch = 0; ch < NCH; ch++) {
        if (ch) __syncthreads();               // prev iteration's LDS reads done
        *(int4*)&Xs[spx * 40 + sh * 16] = xr0;
        *(int4*)&Xs[spx * 40 + sh * 16 + 8] = xr1;
        *(int4*)&Wsh[swr * 40 + swc * 8] = wr0;
        if (ch + 1 < NCH) {                    // prefetch next step into regs
            xr0 = *(const int4*)(xsrc + (ch + 1) * 32);
            xr1 = *(const int4*)(xsrc + (ch + 1) * 32 + 8);
            wr0 = *(const int4*)(wsrc + (ch + 1) * 32);
        }
        __syncthreads();                       // staged data visible
        bf16x8 af[4];
#pragma unroll
        for (int mi = 0; mi < 4; mi++)
            af[mi] = *(const bf16x8*)&Wsh[(mi * 16 + l16) * 40 + quad * 8];
        bf16x8 bf0 = *(const bf16x8*)&Xs[(wave * 32 + l16) * 40 + quad * 8];
        bf16x8 bf1 = *(const bf16x8*)&Xs[(wave * 32 + 16 + l16) * 40 + quad * 8];
#pragma unroll
        for (int mi = 0; mi < 4; mi++) {
            acc[mi][0] = __builtin_amdgcn_mfma_f32_16x16x32_bf16(af[mi], bf0, acc[mi][0], 0, 0, 0);
            acc[mi][1] = __builtin_amdgcn_mfma_f32_16x16x32_bf16(af[mi], bf1, acc[mi][1], 0, 0, 0);
        }
    }
#pragma unroll
    for (int mi = 0; mi < 4; mi++) {
#pragma unroll
        for (int ni = 0; ni < 2; ni++) {
            int c0 = m0 + mi * 16 + quad * 4;
            int px = n0 + wave * 32 + ni * 16 + l16;
            if (MODE == 0) {
                u16* ob = (u16*)outp + ((size_t)b * CO + c0) * HW + px;
#pragma unroll
                for (int rr = 0; rr < 4; rr++) ob[(size_t)rr * HW] = f2bf(acc[mi][ni][rr]);
            } else {
                const float* rp = (const float*)resid + ((size_t)b * 192 + c0) * HW + px;
                ushort4 o;
                o.x = f2bf(acc[mi][ni][0] + rp[0]);
                o.y = f2bf(acc[mi][ni][1] + rp[(size_t)HW]);
                o.z = f2bf(acc[mi][ni][2] + rp[(size_t)2 * HW]);
                o.w = f2bf(acc[mi][ni][3] + rp[(size_t)3 * HW]);
                *(ushort4*)((u16*)outp + ((size_t)b * HW + px) * 192 + c0) = o;
            }
        }
    }
}

// ---------------- K2m: conv1x1 GEMM, X-panel-resident in LDS, m-loop ---------
// X: [b][HW][CIP] bf16 T. The whole 128-px X panel (128 x CIP) is staged ONCE
// (pitch CIP+8); then MT m-tiles of 64 rows: W tile (64 x CIP) staged whole
// with register prefetch one tile ahead -> 2 barriers per 48*NCH/6 MFMA and X
// read from global exactly once. Out bf16 [b][CO][HW] (MODE-0 semantics).
template <int NCH, int MT>
__global__ __launch_bounds__(256) void k_gemm_tm(
    const u16* __restrict__ X, const u16* __restrict__ Wb,
    u16* __restrict__ outp, int CO) {
    constexpr int CIP = NCH * 32;
    constexpr int XP = CIP + 8;
    __shared__ __align__(16) u16 Xs[128 * XP];
    __shared__ __align__(16) u16 Wt[64 * XP];
    const int tid = threadIdx.x;
    const int n0 = blockIdx.x * 128;
    const int b = blockIdx.y;
    const int wave = tid >> 6, lane = tid & 63;
    const int quad = lane >> 4, l16 = lane & 15;
    {   // stage full X panel: row = tid>>1, half = tid&1 (CIP/2 u16 each)
        const int row = tid >> 1, half = tid & 1;
        const u16* xs = X + ((size_t)b * HW + n0 + row) * CIP + half * (CIP / 2);
        u16* xd = &Xs[row * XP + half * (CIP / 2)];
#pragma unroll
        for (int i = 0; i < CIP / 16; i++)
            *(int4*)(xd + i * 8) = *(const int4*)(xs + i * 8);
    }
    // W prefetch: row = tid>>2, quarter = tid&3 (CIP/4 u16 = CIP/32 int4 each)
    const int wrow = tid >> 2, wqk = tid & 3;
    const u16* wsrc0 = Wb + (size_t)wrow * CIP + wqk * (CIP / 4);
    int4 wreg[CIP / 32];
#pragma unroll
    for (int i = 0; i < CIP / 32; i++)
        wreg[i] = *(const int4*)(wsrc0 + i * 8);
    for (int ml = 0; ml < MT; ml++) {
        if (ml) __syncthreads();            // prev m-tile done reading Wt
        {
            u16* wd = &Wt[wrow * XP + wqk * (CIP / 4)];
#pragma unroll
            for (int i = 0; i < CIP / 32; i++) *(int4*)(wd + i * 8) = wreg[i];
        }
        if (ml + 1 < MT) {                  // prefetch next W tile into regs
            const u16* ws = wsrc0 + (size_t)(ml + 1) * 64 * CIP;
#pragma unroll
            for (int i = 0; i < CIP / 32; i++) wreg[i] = *(const int4*)(ws + i * 8);
        }
        __syncthreads();                    // Wt (and, on ml=0, Xs) visible
        f32x4 acc[4][2] = {};
#pragma unroll
        for (int ch = 0; ch < NCH; ch++) {
            bf16x8 af[4];
#pragma unroll
            for (int mi = 0; mi < 4; mi++)
                af[mi] = *(const bf16x8*)&Wt[(mi * 16 + l16) * XP + ch * 32 + quad * 8];
            bf16x8 bf0 = *(const bf16x8*)&Xs[(wave * 32 + l16) * XP + ch * 32 + quad * 8];
            bf16x8 bf1 = *(const bf16x8*)&Xs[(wave * 32 + 16 + l16) * XP + ch * 32 + quad * 8];
#pragma unroll
            for (int mi = 0; mi < 4; mi++) {
                acc[mi][0] = __builtin_amdgcn_mfma_f32_16x16x32_bf16(af[mi], bf0, acc[mi][0], 0, 0, 0);
                acc[mi][1] = __builtin_amdgcn_mfma_f32_16x16x32_bf16(af[mi], bf1, acc[mi][1], 0, 0, 0);
            }
        }
        const int m0 = ml * 64;
#pragma unroll
        for (int mi = 0; mi < 4; mi++)
#pragma unroll
            for (int ni = 0; ni < 2; ni++) {
                int c0 = m0 + mi * 16 + quad * 4;
                int px = n0 + wave * 32 + ni * 16 + l16;
                u16* ob = outp + ((size_t)b * CO + c0) * HW + px;
#pragma unroll
                for (int rr = 0; rr < 4; rr++) ob[(size_t)rr * HW] = f2bf(acc[mi][ni][rr]);
            }
    }
}

// ---------------- K2po: po conv1x1 GEMM (M=192, BN=64) + resid + fused LN2 ---
__global__ __launch_bounds__(256) void k_gemm_po(
    const u16* __restrict__ X, const u16* __restrict__ Wb,
    const float* __restrict__ resid, const float* __restrict__ A2,
    const float* __restrict__ B2, u16* __restrict__ x1T, u16* __restrict__ y0T) {
    constexpr int CIP = 192;
    __shared__ __align__(16) u16 Xs[64 * 40];
    __shared__ __align__(16) u16 Wsh[192 * 40];
    const int tid = threadIdx.x;
    const int n0 = blockIdx.x * 64;
    const int b = blockIdx.y;
    const int wave = tid >> 6, lane = tid & 63;
    const int quad = lane >> 4, l16 = lane & 15;
    const int spx = tid >> 2, sk = tid & 3;     // X: px(0..63), k-chunk(8 u16)
    const u16* xsrc = X + ((size_t)b * HW + n0 + spx) * CIP + sk * 8;
    const u16* wsrc = Wb + (size_t)spx * CIP + sk * 8;   // rows spx, +64, +128
    int4 xr = *(const int4*)xsrc;
    int4 w0 = *(const int4*)(wsrc);
    int4 w1 = *(const int4*)(wsrc + 64 * CIP);
    int4 w2 = *(const int4*)(wsrc + 128 * CIP);
    f32x4 acc[12] = {};
#pragma unroll
    for (int ch = 0; ch < 6; ch++) {
        if (ch) __syncthreads();
        *(int4*)&Xs[spx * 40 + sk * 8] = xr;
        *(int4*)&Wsh[spx * 40 + sk * 8] = w0;
        *(int4*)&Wsh[(spx + 64) * 40 + sk * 8] = w1;
        *(int4*)&Wsh[(spx + 128) * 40 + sk * 8] = w2;
        if (ch + 1 < 6) {
            xr = *(const int4*)(xsrc + (ch + 1) * 32);
            w0 = *(const int4*)(wsrc + (ch + 1) * 32);
            w1 = *(const int4*)(wsrc + 64 * CIP + (ch + 1) * 32);
            w2 = *(const int4*)(wsrc + 128 * CIP + (ch + 1) * 32);
        }
        __syncthreads();
        bf16x8 bf = *(const bf16x8*)&Xs[(wave * 16 + l16) * 40 + quad * 8];
#pragma unroll
        for (int mi = 0; mi < 12; mi++) {
            bf16x8 af = *(const bf16x8*)&Wsh[(mi * 16 + l16) * 40 + quad * 8];
            acc[mi] = __builtin_amdgcn_mfma_f32_16x16x32_bf16(af, bf, acc[mi], 0, 0, 0);
        }
    }
    // epilogue: x1 = acc + resid; per-pixel LN2 over 192 ch; write x1T & y0T.
    int px = n0 + wave * 16 + l16;
    float v[48];
    float s = 0.f, s2 = 0.f;
    const float* rb = resid + (size_t)b * 192 * HW + px;
#pragma unroll
    for (int mi = 0; mi < 12; mi++) {
        int c0 = mi * 16 + quad * 4;
#pragma unroll
        for (int r = 0; r < 4; r++) {
            float val = acc[mi][r] + rb[(size_t)(c0 + r) * HW];
            v[mi * 4 + r] = val; s += val; s2 += val * val;
        }
    }
    s += __shfl_xor(s, 16, 64);  s += __shfl_xor(s, 32, 64);
    s2 += __shfl_xor(s2, 16, 64); s2 += __shfl_xor(s2, 32, 64);
    float mu = s * (1.0f / CDIM);
    float rstd = rsqrtf(s2 * (1.0f / CDIM) - mu * mu + 1e-5f);
    u16* xd = x1T + ((size_t)b * HW + px) * 192;
    u16* yd = y0T + ((size_t)b * HW + px) * 192;
#pragma unroll
    for (int mi = 0; mi < 12; mi++) {
        int c0 = mi * 16 + quad * 4;
        float4 a4 = *(const float4*)(A2 + b * 192 + c0);
        float4 b4 = *(const float4*)(B2 + b * 192 + c0);
        ushort4 xo, yo;
        xo.x = f2bf(v[mi * 4 + 0]); xo.y = f2bf(v[mi * 4 + 1]);
        xo.z = f2bf(v[mi * 4 + 2]); xo.w = f2bf(v[mi * 4 + 3]);
        yo.x = f2bf((v[mi * 4 + 0] - mu) * rstd * a4.x + b4.x);
        yo.y = f2bf((v[mi * 4 + 1] - mu) * rstd * a4.y + b4.y);
        yo.z = f2bf((v[mi * 4 + 2] - mu) * rstd * a4.z + b4.z);
        yo.w = f2bf((v[mi * 4 + 3] - mu) * rstd * a4.w + b4.w);
        *(ushort4*)(xd + c0) = xo;
        *(ushort4*)(yd + c0) = yo;
    }
}

// ---------------- K2s: staged conv1x1 GEMM for pout (input [ch][px] layout) --
__global__ __launch_bounds__(256) void k_gemm_s(
    const u16* __restrict__ X, const u16* __restrict__ Wb,
    const u16* __restrict__ residT, float* __restrict__ outp) {
    constexpr int NCH = 12;
    constexpr int CIP = NCH * 32;
    __shared__ __align__(16) u16 Ws[64 * 32];
    __shared__ __align__(16) u16 Xs[32 * 130];
    const int tid = threadIdx.x;
    const int n0 = blockIdx.x * 128;
    const int m0 = blockIdx.y * 64;
    const int b = blockIdx.z;
    const u16* Xb = X + (size_t)b * 384 * HW + n0;
    const int wave = tid >> 6, lane = tid & 63;
    const int quad = lane >> 4, l16 = lane & 15;
    const int smr = tid >> 2, sk4 = tid & 3;
    const int skr = tid >> 3, sc0 = (tid & 7) * 16;
    f32x4 acc[4][2] = {};
    for (int ch = 0; ch < NCH; ch++) {
        const int k0 = ch * 32;
        if (ch) __syncthreads();
        {
            const int4 wv = *(const int4*)(Wb + (size_t)(m0 + smr) * CIP + k0 + sk4 * 8);
            *(int4*)&Ws[(smr << 5) + (((sk4 ^ (smr & 3)) & 3) << 3)] = wv;
        }
        {
            const u16* xc = Xb + (size_t)(k0 + skr) * HW + sc0;
            int4 r0 = *(const int4*)xc;
            int4 r1 = *(const int4*)(xc + 8);
            u32* dst = (u32*)&Xs[skr * 130 + sc0];
#pragma unroll
            for (int i = 0; i < 4; i++) dst[i] = ((const u32*)&r0)[i];
#pragma unroll
            for (int i = 0; i < 4; i++) dst[4 + i] = ((const u32*)&r1)[i];
        }
        __syncthreads();
        bf16x8 af[4];
#pragma unroll
        for (int mi = 0; mi < 4; mi++) {
            int row = mi * 16 + l16;
            af[mi] = *(const bf16x8*)&Ws[(row << 5) + ((quad ^ (row & 3)) << 3)];
        }
#pragma unroll
        for (int ni = 0; ni < 2; ni++) {
            int n = wave * 32 + ni * 16 + l16;
            bf16x8 bfr;
#pragma unroll
            for (int j = 0; j < 8; j++) bfr[j] = (short)Xs[(quad * 8 + j) * 130 + n];
#pragma unroll
            for (int mi = 0; mi < 4; mi++)
                acc[mi][ni] = __builtin_amdgcn_mfma_f32_16x16x32_bf16(af[mi], bfr, acc[mi][ni], 0, 0, 0);
        }
    }
#pragma unroll
    for (int mi = 0; mi < 4; mi++) {
#pragma unroll
        for (int ni = 0; ni < 2; ni++) {
            int c0 = m0 + mi * 16 + quad * 4;
            int px = n0 + wave * 32 + ni * 16 + l16;
            ushort4 rv = *(const ushort4*)(residT + ((size_t)b * HW + px) * 192 + c0);
            float* ob = outp + ((size_t)b * 192 + c0) * HW + px;
            ob[0] = acc[mi][ni][0] + bf2f(rv.x);
            ob[(size_t)HW] = acc[mi][ni][1] + bf2f(rv.y);
            ob[(size_t)2 * HW] = acc[mi][ni][2] + bf2f(rv.z);
            ob[(size_t)3 * HW] = acc[mi][ni][3] + bf2f(rv.w);
        }
    }
}

// ---------------- K3: depthwise 3x3, LDS-tiled (float4 staging), sumsq -------
__global__ __launch_bounds__(256) void k_dw2(const u16* __restrict__ X,
                                             const float* __restrict__ Wd,
                                             u16* __restrict__ out, int C, int sqCh,
                                             float* __restrict__ sqp) {
    __shared__ float In[34 * 136];   // data cols at +4; borders at idx 3 / 132
    __shared__ float red[4];
    int bc = blockIdx.x >> 2, rt = blockIdx.x & 3;
    int b = bc / C, ch = bc % C;
    const u16* xb = X + (size_t)bc * HW;
    int t = threadIdx.x;
    int c0 = (t & 7) * 16;
    for (int r = t >> 3; r < 34; r += 32) {
        int y = rt * 32 - 1 + r;
        float* dst = &In[r * 136 + 4 + c0];
        if ((unsigned)y < 128u) {
            const u16* src = xb + y * 128 + c0;
            int4 r0 = *(const int4*)src;
            int4 r1 = *(const int4*)(src + 8);
            const u16* p0 = (const u16*)&r0;
            const u16* p1 = (const u16*)&r1;
            float4 f0 = {bf2f(p0[0]), bf2f(p0[1]), bf2f(p0[2]), bf2f(p0[3])};
            float4 f1 = {bf2f(p0[4]), bf2f(p0[5]), bf2f(p0[6]), bf2f(p0[7])};
            float4 f2 = {bf2f(p1[0]), bf2f(p1[1]), bf2f(p1[2]), bf2f(p1[3])};
            float4 f3 = {bf2f(p1[4]), bf2f(p1[5]), bf2f(p1[6]), bf2f(p1[7])};
            *(float4*)(dst) = f0;      *(float4*)(dst + 4) = f1;
            *(float4*)(dst + 8) = f2;  *(float4*)(dst + 12) = f3;
        } else {
            float4 z = {0.f, 0.f, 0.f, 0.f};
            *(float4*)(dst) = z;      *(float4*)(dst + 4) = z;
            *(float4*)(dst + 8) = z;  *(float4*)(dst + 12) = z;
        }
    }
    if (t < 34) { In[t * 136 + 3] = 0.f; In[t * 136 + 132] = 0.f; }
    __syncthreads();
    const float* w = Wd + ch * 9;
    float w00 = w[0], w01 = w[1], w02 = w[2], w10 = w[3], w11 = w[4],
          w12 = w[5], w20 = w[6], w21 = w[7], w22 = w[8];
    int x = t & 127, rg = t >> 7;
    int base = rg * 16;
    float A2 = 0.f, A1 = 0.f, B1 = 0.f, ssq = 0.f;
    u16* ob = out + (size_t)bc * HW + (rt * 32 + base) * 128 + x;
#pragma unroll
    for (int r = 0; r < 18; r++) {
        const float* row = &In[(base + r) * 136 + 3 + x];
        float v0 = row[0], v1 = row[1], v2 = row[2];
        float h0 = w00 * v0 + w01 * v1 + w02 * v2;
        float h1 = w10 * v0 + w11 * v1 + w12 * v2;
        float h2 = w20 * v0 + w21 * v1 + w22 * v2;
        if (r >= 2) {
            float val = A2 + B1 + h2;
            ob[(size_t)(r - 2) * 128] = f2bf(val);
            ssq += val * val;
        }
        A2 = A1; A1 = h0; B1 = h1;
    }
    if (ch < sqCh) {   // block-uniform branch
        for (int o = 32; o > 0; o >>= 1) ssq += __shfl_down(ssq, o, 64);
        int wid = t >> 6, lane = t & 63;
        if (lane == 0) red[wid] = ssq;
        __syncthreads();
        if (t == 0) sqp[((b * 192 + ch) << 2) | rt] = red[0] + red[1] + red[2] + red[3];
    }
}

// ---------------- K3b: depthwise 3x3 pair + exact GELU gate (float4 staging) -
__global__ __launch_bounds__(256) void k_dw_gelu2(const u16* __restrict__ G0,
                                                  const float* __restrict__ Wd,
                                                  u16* __restrict__ out) {
    __shared__ float In[2 * 34 * 136];
    int bc = blockIdx.x >> 2, rt = blockIdx.x & 3;
    int b = bc / 384, j = bc % 384;
    int t = threadIdx.x;
    int c0 = (t & 7) * 16;
    for (int pl = 0; pl < 2; pl++) {
        const u16* xb = G0 + ((size_t)b * 768 + pl * 384 + j) * HW;
        float* pla = &In[pl * 34 * 136];
        for (int r = t >> 3; r < 34; r += 32) {
            int y = rt * 32 - 1 + r;
            float* dst = &pla[r * 136 + 4 + c0];
            if ((unsigned)y < 128u) {
                const u16* src = xb + y * 128 + c0;
                int4 r0 = *(const int4*)src;
                int4 r1 = *(const int4*)(src + 8);
                const u16* p0 = (const u16*)&r0;
                const u16* p1 = (const u16*)&r1;
                float4 f0 = {bf2f(p0[0]), bf2f(p0[1]), bf2f(p0[2]), bf2f(p0[3])};
                float4 f1 = {bf2f(p0[4]), bf2f(p0[5]), bf2f(p0[6]), bf2f(p0[7])};
                float4 f2 = {bf2f(p1[0]), bf2f(p1[1]), bf2f(p1[2]), bf2f(p1[3])};
                float4 f3 = {bf2f(p1[4]), bf2f(p1[5]), bf2f(p1[6]), bf2f(p1[7])};
                *(float4*)(dst) = f0;      *(float4*)(dst + 4) = f1;
                *(float4*)(dst + 8) = f2;  *(float4*)(dst + 12) = f3;
            } else {
                float4 z = {0.f, 0.f, 0.f, 0.f};
                *(float4*)(dst) = z;      *(float4*)(dst + 4) = z;
                *(float4*)(dst + 8) = z;  *(float4*)(dst + 12) = z;
            }
        }
        if (t < 34) { pla[t * 136 + 3] = 0.f; pla[t * 136 + 132] = 0.f; }
    }
    __syncthreads();
    const float* w1 = Wd + j * 9;
    const float* w2 = Wd + (384 + j) * 9;
    float a00 = w1[0], a01 = w1[1], a02 = w1[2], a10 = w1[3], a11 = w1[4],
          a12 = w1[5], a20 = w1[6], a21 = w1[7], a22 = w1[8];
    float b00 = w2[0], b01 = w2[1], b02 = w2[2], b10 = w2[3], b11 = w2[4],
          b12 = w2[5], b20 = w2[6], b21 = w2[7], b22 = w2[8];
    int x = t & 127, rg = t >> 7;
    int base = rg * 16;
    float A2a = 0.f, A1a = 0.f, B1a = 0.f;
    float A2b = 0.f, A1b = 0.f, B1b = 0.f;
    u16* ob = out + ((size_t)b * 384 + j) * HW + (rt * 32 + base) * 128 + x;
#pragma unroll
    for (int r = 0; r < 18; r++) {
        const float* r1p = &In[(base + r) * 136 + 3 + x];
        const float* r2p = r1p + 34 * 136;
        float u0 = r1p[0], u1 = r1p[1], u2 = r1p[2];
        float v0 = r2p[0], v1 = r2p[1], v2 = r2p[2];
        float h0a = a00 * u0 + a01 * u1 + a02 * u2;
        float h1a = a10 * u0 + a11 * u1 + a12 * u2;
        float h2a = a20 * u0 + a21 * u1 + a22 * u2;
        float h0b = b00 * v0 + b01 * v1 + b02 * v2;
        float h1b = b10 * v0 + b11 * v1 + b12 * v2;
        float h2b = b20 * v0 + b21 * v1 + b22 * v2;
        if (r >= 2) {
            float s1 = A2a + B1a + h2a;
            float s2 = A2b + B1b + h2b;
            float g = 0.5f * s1 * (1.0f + erff(s1 * 0.70710678118654752f));
            ob[(size_t)(r - 2) * 128] = f2bf(g * s2);
        }
        A2a = A1a; A1a = h0a; B1a = h1a;
        A2b = A1b; A1b = h0b; B1b = h1b;
    }
}

// ---------------- K5: S partials = Q*K^T via MFMA, 64 d-chunks, prefetch -----
__global__ __launch_bounds__(256) void k_qk(const u16* __restrict__ qb_,
                                            const u16* __restrict__ kb_,
                                            float* __restrict__ Spart) {
    int bh = blockIdx.x >> 6, ds = blockIdx.x & 63;   // 768 blocks
    int b = bh / HEADS, h = bh % HEADS;
    int tid = threadIdx.x;
    int wave = tid >> 6, lane = tid & 63;
    int quad = lane >> 4, l16 = lane & 15;
    int tm = wave >> 1, tn = wave & 1;
    const u16* qrow = qb_ + ((size_t)(b * 192 + h * 32 + tm * 16 + l16)) * HW + ds * 256 + quad * 8;
    const u16* krow = kb_ + ((size_t)(b * 384 + h * 32 + tn * 16 + l16)) * HW + ds * 256 + quad * 8;
    f32x4 acc = {};
    bf16x8 qa[3], ka[3];
    auto ld = [&](int s, int cc) {
        qa[s] = *(const bf16x8*)(qrow + cc * 32);
        ka[s] = *(const bf16x8*)(krow + cc * 32);
    };
    ld(0, 0); ld(1, 1);
#pragma unroll
    for (int ch = 0; ch < 8; ch++) {
        if (ch + 2 < 8) ld((ch + 2) % 3, ch + 2);
        acc = __builtin_amdgcn_mfma_f32_16x16x32_bf16(qa[ch % 3], ka[ch % 3], acc, 0, 0, 0);
    }
    float* Sb = Spart + ((size_t)ds * 12 + bh) * 1024;
#pragma unroll
    for (int r = 0; r < 4; r++)
        Sb[(tm * 16 + quad * 4 + r) * 32 + tn * 16 + l16] = acc[r];
}

// ---------------- K6: reduce partials + normalize + softmax, bf16 out --------
__global__ void k_softmax(const float* __restrict__ Spart, const float* __restrict__ sqqp,
                          const float* __restrict__ sqkp, const float* __restrict__ temp,
                          u16* __restrict__ attnb) {
    int row = blockIdx.x;           // 0..383
    int bh = row >> 5, c2 = row & 31;
    int b = bh / HEADS, h = bh % HEADS;
    int e = threadIdx.x;            // 64 threads, active e<32
    float l = -1e30f;
    if (e < 32) {
        float s = 0.f;
        for (int d = 0; d < 64; d++) s += Spart[((size_t)d * 12 + bh) * 1024 + c2 * 32 + e];
        const float* qp = sqqp + (b * 192 + h * 32 + c2) * 4;
        const float* kp = sqkp + (b * 192 + h * 32 + e) * 4;
        float nq = qp[0] + qp[1] + qp[2] + qp[3];
        float nk = kp[0] + kp[1] + kp[2] + kp[3];
        float invq = 1.0f / fmaxf(sqrtf(nq), 1e-12f);
        float invk = 1.0f / fmaxf(sqrtf(nk), 1e-12f);
        l = s * invq * invk * temp[h];
    }
    float m = l;
    for (int o = 32; o > 0; o >>= 1) m = fmaxf(m, __shfl_xor(m, o, 64));
    float ev = (e < 32) ? expf(l - m) : 0.f;
    float ssum = ev;
    for (int o = 32; o > 0; o >>= 1) ssum += __shfl_xor(ssum, o, 64);
    if (e < 32) attnb[bh * 1024 + c2 * 32 + e] = f2bf(ev / ssum);
}

// ---------------- K7: out = attn @ V via MFMA, TRANSPOSED out [b][px][192] ---
__global__ __launch_bounds__(256) void k_av(const u16* __restrict__ attnb,
                                            const u16* __restrict__ kvb,
                                            u16* __restrict__ out) {
    __shared__ __align__(16) u16 Vs[32 * 130];
    int bh = blockIdx.x >> 7;       // 12
    int pt = blockIdx.x & 127;
    int b = bh / HEADS, h = bh % HEADS;
    int p0 = pt * 128;
    int t = threadIdx.x;
    {
        int e = t >> 3, c0 = (t & 7) * 16;
        const u16* src = kvb + ((size_t)(b * 384 + 192 + h * 32 + e)) * HW + p0 + c0;
        int4 r0 = *(const int4*)src;
        int4 r1 = *(const int4*)(src + 8);
        u32* dst = (u32*)&Vs[e * 130 + c0];
#pragma unroll
        for (int i = 0; i < 4; i++) dst[i] = ((const u32*)&r0)[i];
#pragma unroll
        for (int i = 0; i < 4; i++) dst[4 + i] = ((const u32*)&r1)[i];
    }
    __syncthreads();
    int wave = t >> 6, lane = t & 63;
    int quad = lane >> 4, l16 = lane & 15;
    f32x4 acc[2][2] = {};
    bf16x8 af[2];
#pragma unroll
    for (int tm = 0; tm < 2; tm++)
        af[tm] = *(const bf16x8*)(attnb + bh * 1024 + (tm * 16 + l16) * 32 + quad * 8);
#pragma unroll
    for (int nt = 0; nt < 2; nt++) {
        int n = wave * 32 + nt * 16 + l16;
        bf16x8 bfr;
#pragma unroll
        for (int j = 0; j < 8; j++) bfr[j] = (short)Vs[(quad * 8 + j) * 130 + n];
#pragma unroll
        for (int tm = 0; tm < 2; tm++)
            acc[tm][nt] = __builtin_amdgcn_mfma_f32_16x16x32_bf16(af[tm], bfr, acc[tm][nt], 0, 0, 0);
    }
#pragma unroll
    for (int tm = 0; tm < 2; tm++)
#pragma unroll
        for (int nt = 0; nt < 2; nt++) {
            int c0 = h * 32 + tm * 16 + quad * 4;
            int px = p0 + wave * 32 + nt * 16 + l16;
            ushort4 o;
            o.x = f2bf(acc[tm][nt][0]);
            o.y = f2bf(acc[tm][nt][1]);
            o.z = f2bf(acc[tm][nt][2]);
            o.w = f2bf(acc[tm][nt][3]);
            *(ushort4*)(out + ((size_t)b * HW + px) * 192 + c0) = o;
        }
}

extern "C" void kernel_launch(void* const* d_in, const int* in_sizes, int n_in,
                              void* d_out, int out_size, void* d_ws, size_t ws_size,
                              hipStream_t stream) {
    const float* x     = (const float*)d_in[0];
    const float* k_v   = (const float*)d_in[1];
    const float* ln1w  = (const float*)d_in[2];
    const float* ln1b  = (const float*)d_in[3];
    const float* temp  = (const float*)d_in[4];
    const float* w_kR  = (const float*)d_in[5];
    const float* w_kI  = (const float*)d_in[6];
    const float* w_qR  = (const float*)d_in[7];
    const float* w_qdw = (const float*)d_in[8];
    const float* w_kvI = (const float*)d_in[9];
    const float* w_kvdw= (const float*)d_in[10];
    const float* w_po  = (const float*)d_in[11];
    const float* ln2w  = (const float*)d_in[12];
    const float* ln2b  = (const float*)d_in[13];
    const float* w_ffk = (const float*)d_in[14];
    const float* w_pin = (const float*)d_in[15];
    const float* w_dw  = (const float*)d_in[16];
    const float* w_pout= (const float*)d_in[17];
    float* out = (float*)d_out;

    const size_t MiB = 1048576ULL;
    // Region plan (disjoint lifetimes; peak ~150 MiB):
    u16*   q0b     = wsh(d_ws, 0);          // [2][192][HW] std; reused: Spart, attnoutT, y0T
    u16*   attnoutb= wsh(d_ws, 0);          // [2][HW][192] T
    u16*   y0b     = wsh(d_ws, 0);          // [2][HW][192] T (k_gemm_po: same-block alias, safe)
    u16*   kv0b    = wsh(d_ws, 12 * MiB);   // [2][384][HW] std; reused: ybuf
    u16*   ybufb   = wsh(d_ws, 12 * MiB);
    u16*   x1b     = wsh(d_ws, 36 * MiB);   // [2][HW][192] T (po->pout resid)
    u16*   qbuf_b  = wsh(d_ws, 48 * MiB);   // [2][192][HW] std (dwq->qk)
    u16*   kvbuf_b = wsh(d_ws, 60 * MiB);   // [2][384][HW] std (dwkv->qk/av)
    u16*   xrb     = wsh(d_ws, 84 * MiB);   // [2][HW][160] T (exact 10 MiB)
    u16*   xib     = wsh(d_ws, 94 * MiB);   // [2][HW][64]  T (exact 4 MiB)
    u16*   g0b     = wsh(d_ws, 98 * MiB);   // [2][768][HW] std (pin->gelu)
    u16*   wb      = wsh(d_ws, 146 * MiB);  // bf16 weights, 627 KB
    float* sm      = wsf(d_ws, 147 * MiB);  // smalls
    float* Spart   = wsf(d_ws, 0);          // 64*12*1024 fp32 = 3 MiB over dead q0b
    u16* wq   = wb;            // [192][160]
    u16* wkv  = wb + 30720;    // [384][64]
    u16* wpo  = wb + 55296;    // [192][192]
    u16* wpin = wb + 92160;    // [768][192]
    u16* wpout= wb + 239616;   // [192][384]
    float* kvr  = sm;               // 288
    float* kvi  = sm + 288;         // 96
    // kvf = sm + 384 (written, unused directly)
    float* sqqp = sm + 768;         // 1536 (4 row-tile partials x 384 rows)
    float* sqkp = sm + 2304;        // 1536
    u16*   attnb= (u16*)(sm + 3840);// 12288 bf16 (ends at float 9984)
    float* A2c  = sm + 10240;       // 384 (ln2w * (kvf+1))
    float* B2c  = sm + 10624;       // 384 (ln2b * (kvf+1))

    k_setup<<<1229, 256, 0, stream>>>(k_v, w_kR, w_kI, w_ffk, w_qR, w_kvI, w_po,
                                      w_pin, w_pout, ln2w, ln2b, wb, sm, A2c, B2c,
                                      out + (size_t)NB * CDIM * HW);
    k_ln1<<<NPX / 64, 256, 0, stream>>>(x, ln1w, ln1b, kvr, kvi, xrb, xib);
    k_gemm_t<5, 0><<<dim3(128, 3, 2), 256, 0, stream>>>(xrb, wq, nullptr, q0b, 192);
    k_gemm_t<2, 0><<<dim3(128, 6, 2), 256, 0, stream>>>(xib, wkv, nullptr, kv0b, 384);
    k_dw2<<<NB * 192 * 4, 256, 0, stream>>>(q0b, w_qdw, qbuf_b, 192, 192, sqqp);
    k_dw2<<<NB * 384 * 4, 256, 0, stream>>>(kv0b, w_kvdw, kvbuf_b, 384, 192, sqkp);
    k_qk<<<12 * 64, 256, 0, stream>>>(qbuf_b, kvbuf_b, Spart);
    k_softmax<<<384, 64, 0, stream>>>(Spart, sqqp, sqkp, temp, attnb);
    k_av<<<12 * 128, 256, 0, stream>>>(attnb, kvbuf_b, attnoutb);
    k_gemm_po<<<dim3(256, 2), 256, 0, stream>>>(attnoutb, wpo, x, A2c, B2c, x1b, y0b);
    k_gemm_tm<6, 12><<<dim3(128, 2), 256, 0, stream>>>(y0b, wpin, g0b, 768);
    k_dw_gelu2<<<NB * 384 * 4, 256, 0, stream>>>(g0b, w_dw, ybufb);
    k_gemm_s<<<dim3(128, 3, 2), 256, 0, stream>>>(ybufb, wpout, x1b, out);
}

// Round 10
// 251.697 us; speedup vs baseline: 1.0758x; 1.0758x over previous
//
#include <hip/hip_runtime.h>
#include <math.h>

#define HW 16384
#define CDIM 192
#define C3 144
#define C4 48
#define NB 2
#define NPX 32768   // NB*HW
#define HEADS 6

typedef unsigned short u16;
typedef unsigned int u32;
typedef __attribute__((ext_vector_type(8))) short bf16x8;
typedef __attribute__((ext_vector_type(4))) float f32x4;

__device__ __forceinline__ float bf2f(u16 u) {
    return __uint_as_float(((unsigned int)u) << 16);
}
__device__ __forceinline__ u16 f2bf(float f) {
    unsigned int x = __float_as_uint(f);
    unsigned int r = x + 0x7fffu + ((x >> 16) & 1u);  // RNE
    return (u16)(r >> 16);
}

static inline float* wsf(void* ws, size_t off) { return (float*)((char*)ws + off); }
static inline u16* wsh(void* ws, size_t off) { return (u16*)((char*)ws + off); }

// ---------------- K0: setup = weight bf16 conversion + tiny GEMVs + k_v copy -
__global__ void k_setup(const float* __restrict__ kvv, const float* __restrict__ wkR,
                        const float* __restrict__ wkI, const float* __restrict__ wffk,
                        const float* __restrict__ wqR, const float* __restrict__ wkvI,
                        const float* __restrict__ wpo, const float* __restrict__ wpin,
                        const float* __restrict__ wpout,
                        const float* __restrict__ ln2w, const float* __restrict__ ln2b,
                        u16* __restrict__ wb, float* __restrict__ sm,
                        float* __restrict__ A2, float* __restrict__ B2,
                        float* __restrict__ tail) {
    int t = blockIdx.x * 256 + threadIdx.x;
    if (t < 313344) {
        float v;
        if (t < 30720) {
            int o = t / 160, i = t % 160;
            v = (i < 144) ? wqR[o * 144 + i] : 0.f;
        } else if (t < 55296) {
            int r = t - 30720; int o = r / 64, i = r % 64;
            v = (i < 48) ? wkvI[o * 48 + i] : 0.f;
        } else if (t < 92160) {
            v = wpo[t - 55296];
        } else if (t < 239616) {
            v = wpin[t - 92160];
        } else {
            v = wpout[t - 239616];
        }
        wb[t] = f2bf(v);
    } else if (t < 314112) {
        int r = t - 313344;              // 0..767: modulation GEMVs (stored as val+1)
        if (r < 288) {
            int b = r / 144, o = r % 144;
            const float* v = kvv + b * 256;
            const float* w = wkR + o * 192;
            float s = 0.f;
#pragma unroll 8
            for (int j = 0; j < 192; j++) s += v[j] * w[j];
            sm[r] = s + 1.0f;
        } else if (r < 384) {
            int r2 = r - 288;
            int b = r2 / 48, o = r2 % 48;
            const float* v = kvv + b * 256 + 192;
            const float* w = wkI + o * 64;
            float s = 0.f;
#pragma unroll 8
            for (int j = 0; j < 64; j++) s += v[j] * w[j];
            sm[288 + r2] = s + 1.0f;
        } else {
            int r2 = r - 384;
            int b = r2 / 192, o = r2 % 192;
            const float* v = kvv + b * 256;
            const float* w = wffk + o * 256;
            float s = 0.f;
#pragma unroll 8
            for (int j = 0; j < 256; j++) s += v[j] * w[j];
            float sc = s + 1.0f;
            sm[384 + r2] = sc;
            A2[r2] = ln2w[o] * sc;       // fused LN2 scale
            B2[r2] = ln2b[o] * sc;       // fused LN2 bias
        }
    } else if (t < 314624) {
        int r = t - 314112;
        tail[r] = kvv[r];                // k_v pass-through to output tail
    }
}

// ---------------- K1: LN1 + modulation, single-pass, TRANSPOSED bf16 out -----
__global__ __launch_bounds__(256) void k_ln1(
    const float* __restrict__ xin,
    const float* __restrict__ lnw, const float* __restrict__ lnb,
    const float* __restrict__ sca, const float* __restrict__ scb,
    u16* __restrict__ outA, u16* __restrict__ outB) {
    __shared__ float red[2][16][16][4];
    __shared__ float mu_s[16][4], rstd_s[16][4];
    int t = threadIdx.x;
    int px4 = t & 15, cg = t >> 4;
    int base = blockIdx.x * 64;
    int b = base >> 14;
    int p = (base & 16383) + px4 * 4;
    float vals[12][4];
    float s[4] = {0.f, 0.f, 0.f, 0.f}, s2[4] = {0.f, 0.f, 0.f, 0.f};
#pragma unroll
    for (int j = 0; j < 12; j++) {
        int c = cg * 12 + j;
        size_t off = ((size_t)(b * CDIM + c)) * HW + p;
        float4 f = *(const float4*)(xin + off);
        float v[4] = {f.x, f.y, f.z, f.w};
#pragma unroll
        for (int q = 0; q < 4; q++) {
            vals[j][q] = v[q]; s[q] += v[q]; s2[q] += v[q] * v[q];
        }
    }
#pragma unroll
    for (int q = 0; q < 4; q++) { red[0][cg][px4][q] = s[q]; red[1][cg][px4][q] = s2[q]; }
    __syncthreads();
    if (t < 16) {
        float S[4] = {0.f, 0.f, 0.f, 0.f}, S2[4] = {0.f, 0.f, 0.f, 0.f};
        for (int g2 = 0; g2 < 16; g2++)
#pragma unroll
            for (int q = 0; q < 4; q++) { S[q] += red[0][g2][t][q]; S2[q] += red[1][g2][t][q]; }
#pragma unroll
        for (int q = 0; q < 4; q++) {
            float mu = S[q] * (1.0f / CDIM);
            float var = S2[q] * (1.0f / CDIM) - mu * mu;
            mu_s[t][q] = mu;
            rstd_s[t][q] = rsqrtf(var + 1e-5f);
        }
    }
    __syncthreads();
    float mu[4], rs[4];
#pragma unroll
    for (int q = 0; q < 4; q++) { mu[q] = mu_s[px4][q]; rs[q] = rstd_s[px4][q]; }
    float Ac[12], Bc[12];
#pragma unroll
    for (int j = 0; j < 12; j++) {
        int c = cg * 12 + j;
        float sc = (c < C3) ? sca[b * C3 + c] : scb[b * C4 + (c - C3)];
        Ac[j] = lnw[c] * sc;
        Bc[j] = lnb[c] * sc;
    }
    int isR = (cg < 12);
    size_t row0 = (size_t)b * HW + p;
    u16* basep = isR ? (outA + row0 * 160 + cg * 12)
                     : (outB + row0 * 64 + (cg * 12 - 144));
    int rowlen = isR ? 160 : 64;
#pragma unroll
    for (int q = 0; q < 4; q++) {
        u16 tmp[12];
#pragma unroll
        for (int j = 0; j < 12; j++)
            tmp[j] = f2bf((vals[j][q] - mu[q]) * rs[q] * Ac[j] + Bc[j]);
        u16* op = basep + q * rowlen;
        ushort4 o0 = {tmp[0], tmp[1], tmp[2], tmp[3]};
        ushort4 o1 = {tmp[4], tmp[5], tmp[6], tmp[7]};
        ushort4 o2 = {tmp[8], tmp[9], tmp[10], tmp[11]};
        *(ushort4*)(op) = o0;
        *(ushort4*)(op + 4) = o1;
        *(ushort4*)(op + 8) = o2;
    }
    if (cg == 0) {   // zero the K-pad columns so garbage never reaches MFMA
        int4 z = {0, 0, 0, 0};
#pragma unroll
        for (int q = 0; q < 4; q++) {
            u16* pr = outA + (row0 + q) * 160 + 144;
            *(int4*)(pr) = z; *(int4*)(pr + 8) = z;
            u16* pi = outB + (row0 + q) * 64 + 48;
            *(int4*)(pi) = z; *(int4*)(pi + 8) = z;
        }
    }
}

// ---------------- K2: conv1x1 GEMM, LDS-staged, all-b128 fragment reads ------
// MODE 0: out bf16 [b][CO][HW].  MODE 1: resid fp32 std, out bf16 [b][HW][192].
template <int NCH, int MODE>
__global__ __launch_bounds__(256) void k_gemm_t(
    const u16* __restrict__ X, const u16* __restrict__ Wb,
    const void* __restrict__ resid, void* __restrict__ outp, int CO) {
    constexpr int CIP = NCH * 32;
    __shared__ __align__(16) u16 Xs[128 * 40];   // [px][32k] pitch 40 u16
    __shared__ __align__(16) u16 Wsh[64 * 40];   // [m][32k]  pitch 40 u16
    const int tid = threadIdx.x;
    const int n0 = blockIdx.x * 128;
    const int m0 = blockIdx.y * 64;
    const int b = blockIdx.z;
    const int wave = tid >> 6, lane = tid & 63;
    const int quad = lane >> 4, l16 = lane & 15;
    const int spx = tid >> 1, sh = tid & 1;    // X stage: px, k-half(16 u16)
    const int swr = tid >> 2, swc = tid & 3;   // W stage: m-row, k-chunk(8 u16)
    const u16* xsrc = X + ((size_t)b * HW + n0 + spx) * CIP + sh * 16;
    const u16* wsrc = Wb + (size_t)(m0 + swr) * CIP + swc * 8;
    int4 xr0 = *(const int4*)(xsrc);
    int4 xr1 = *(const int4*)(xsrc + 8);
    int4 wr0 = *(const int4*)(wsrc);
    f32x4 acc[4][2] = {};
#pragma unroll
    for (int ch = 0; ch < NCH; ch++) {
        if (ch) __syncthreads();               // prev iteration's LDS reads done
        *(int4*)&Xs[spx * 40 + sh * 16] = xr0;
        *(int4*)&Xs[spx * 40 + sh * 16 + 8] = xr1;
        *(int4*)&Wsh[swr * 40 + swc * 8] = wr0;
        if (ch + 1 < NCH) {                    // prefetch next step into regs
            xr0 = *(const int4*)(xsrc + (ch + 1) * 32);
            xr1 = *(const int4*)(xsrc + (ch + 1) * 32 + 8);
            wr0 = *(const int4*)(wsrc + (ch + 1) * 32);
        }
        __syncthreads();                       // staged data visible
        bf16x8 af[4];
#pragma unroll
        for (int mi = 0; mi < 4; mi++)
            af[mi] = *(const bf16x8*)&Wsh[(mi * 16 + l16) * 40 + quad * 8];
        bf16x8 bf0 = *(const bf16x8*)&Xs[(wave * 32 + l16) * 40 + quad * 8];
        bf16x8 bf1 = *(const bf16x8*)&Xs[(wave * 32 + 16 + l16) * 40 + quad * 8];
#pragma unroll
        for (int mi = 0; mi < 4; mi++) {
            acc[mi][0] = __builtin_amdgcn_mfma_f32_16x16x32_bf16(af[mi], bf0, acc[mi][0], 0, 0, 0);
            acc[mi][1] = __builtin_amdgcn_mfma_f32_16x16x32_bf16(af[mi], bf1, acc[mi][1], 0, 0, 0);
        }
    }
#pragma unroll
    for (int mi = 0; mi < 4; mi++) {
#pragma unroll
        for (int ni = 0; ni < 2; ni++) {
            int c0 = m0 + mi * 16 + quad * 4;
            int px = n0 + wave * 32 + ni * 16 + l16;
            if (MODE == 0) {
                u16* ob = (u16*)outp + ((size_t)b * CO + c0) * HW + px;
#pragma unroll
                for (int rr = 0; rr < 4; rr++) ob[(size_t)rr * HW] = f2bf(acc[mi][ni][rr]);
            } else {
                const float* rp = (const float*)resid + ((size_t)b * 192 + c0) * HW + px;
                ushort4 o;
                o.x = f2bf(acc[mi][ni][0] + rp[0]);
                o.y = f2bf(acc[mi][ni][1] + rp[(size_t)HW]);
                o.z = f2bf(acc[mi][ni][2] + rp[(size_t)2 * HW]);
                o.w = f2bf(acc[mi][ni][3] + rp[(size_t)3 * HW]);
                *(ushort4*)((u16*)outp + ((size_t)b * HW + px) * 192 + c0) = o;
            }
        }
    }
}

// ---------------- K2po: po conv1x1 GEMM (M=192, BN=64) + resid + fused LN2 ---
__global__ __launch_bounds__(256) void k_gemm_po(
    const u16* __restrict__ X, const u16* __restrict__ Wb,
    const float* __restrict__ resid, const float* __restrict__ A2,
    const float* __restrict__ B2, u16* __restrict__ x1T, u16* __restrict__ y0T) {
    constexpr int CIP = 192;
    __shared__ __align__(16) u16 Xs[64 * 40];
    __shared__ __align__(16) u16 Wsh[192 * 40];
    const int tid = threadIdx.x;
    const int n0 = blockIdx.x * 64;
    const int b = blockIdx.y;
    const int wave = tid >> 6, lane = tid & 63;
    const int quad = lane >> 4, l16 = lane & 15;
    const int spx = tid >> 2, sk = tid & 3;     // X: px(0..63), k-chunk(8 u16)
    const u16* xsrc = X + ((size_t)b * HW + n0 + spx) * CIP + sk * 8;
    const u16* wsrc = Wb + (size_t)spx * CIP + sk * 8;   // rows spx, +64, +128
    int4 xr = *(const int4*)xsrc;
    int4 w0 = *(const int4*)(wsrc);
    int4 w1 = *(const int4*)(wsrc + 64 * CIP);
    int4 w2 = *(const int4*)(wsrc + 128 * CIP);
    f32x4 acc[12] = {};
#pragma unroll
    for (int ch = 0; ch < 6; ch++) {
        if (ch) __syncthreads();
        *(int4*)&Xs[spx * 40 + sk * 8] = xr;
        *(int4*)&Wsh[spx * 40 + sk * 8] = w0;
        *(int4*)&Wsh[(spx + 64) * 40 + sk * 8] = w1;
        *(int4*)&Wsh[(spx + 128) * 40 + sk * 8] = w2;
        if (ch + 1 < 6) {
            xr = *(const int4*)(xsrc + (ch + 1) * 32);
            w0 = *(const int4*)(wsrc + (ch + 1) * 32);
            w1 = *(const int4*)(wsrc + 64 * CIP + (ch + 1) * 32);
            w2 = *(const int4*)(wsrc + 128 * CIP + (ch + 1) * 32);
        }
        __syncthreads();
        bf16x8 bf = *(const bf16x8*)&Xs[(wave * 16 + l16) * 40 + quad * 8];
#pragma unroll
        for (int mi = 0; mi < 12; mi++) {
            bf16x8 af = *(const bf16x8*)&Wsh[(mi * 16 + l16) * 40 + quad * 8];
            acc[mi] = __builtin_amdgcn_mfma_f32_16x16x32_bf16(af, bf, acc[mi], 0, 0, 0);
        }
    }
    // epilogue: x1 = acc + resid; per-pixel LN2 over 192 ch; write x1T & y0T.
    int px = n0 + wave * 16 + l16;
    float v[48];
    float s = 0.f, s2 = 0.f;
    const float* rb = resid + (size_t)b * 192 * HW + px;
#pragma unroll
    for (int mi = 0; mi < 12; mi++) {
        int c0 = mi * 16 + quad * 4;
#pragma unroll
        for (int r = 0; r < 4; r++) {
            float val = acc[mi][r] + rb[(size_t)(c0 + r) * HW];
            v[mi * 4 + r] = val; s += val; s2 += val * val;
        }
    }
    s += __shfl_xor(s, 16, 64);  s += __shfl_xor(s, 32, 64);
    s2 += __shfl_xor(s2, 16, 64); s2 += __shfl_xor(s2, 32, 64);
    float mu = s * (1.0f / CDIM);
    float rstd = rsqrtf(s2 * (1.0f / CDIM) - mu * mu + 1e-5f);
    u16* xd = x1T + ((size_t)b * HW + px) * 192;
    u16* yd = y0T + ((size_t)b * HW + px) * 192;
#pragma unroll
    for (int mi = 0; mi < 12; mi++) {
        int c0 = mi * 16 + quad * 4;
        float4 a4 = *(const float4*)(A2 + b * 192 + c0);
        float4 b4 = *(const float4*)(B2 + b * 192 + c0);
        ushort4 xo, yo;
        xo.x = f2bf(v[mi * 4 + 0]); xo.y = f2bf(v[mi * 4 + 1]);
        xo.z = f2bf(v[mi * 4 + 2]); xo.w = f2bf(v[mi * 4 + 3]);
        yo.x = f2bf((v[mi * 4 + 0] - mu) * rstd * a4.x + b4.x);
        yo.y = f2bf((v[mi * 4 + 1] - mu) * rstd * a4.y + b4.y);
        yo.z = f2bf((v[mi * 4 + 2] - mu) * rstd * a4.z + b4.z);
        yo.w = f2bf((v[mi * 4 + 3] - mu) * rstd * a4.w + b4.w);
        *(ushort4*)(xd + c0) = xo;
        *(ushort4*)(yd + c0) = yo;
    }
}

// ---------------- K2s: staged conv1x1 GEMM for pout (input [ch][px] layout) --
__global__ __launch_bounds__(256) void k_gemm_s(
    const u16* __restrict__ X, const u16* __restrict__ Wb,
    const u16* __restrict__ residT, float* __restrict__ outp) {
    constexpr int NCH = 12;
    constexpr int CIP = NCH * 32;
    __shared__ __align__(16) u16 Ws[64 * 32];
    __shared__ __align__(16) u16 Xs[32 * 130];
    const int tid = threadIdx.x;
    const int n0 = blockIdx.x * 128;
    const int m0 = blockIdx.y * 64;
    const int b = blockIdx.z;
    const u16* Xb = X + (size_t)b * 384 * HW + n0;
    const int wave = tid >> 6, lane = tid & 63;
    const int quad = lane >> 4, l16 = lane & 15;
    const int smr = tid >> 2, sk4 = tid & 3;
    const int skr = tid >> 3, sc0 = (tid & 7) * 16;
    f32x4 acc[4][2] = {};
    for (int ch = 0; ch < NCH; ch++) {
        const int k0 = ch * 32;
        if (ch) __syncthreads();
        {
            const int4 wv = *(const int4*)(Wb + (size_t)(m0 + smr) * CIP + k0 + sk4 * 8);
            *(int4*)&Ws[(smr << 5) + (((sk4 ^ (smr & 3)) & 3) << 3)] = wv;
        }
        {
            const u16* xc = Xb + (size_t)(k0 + skr) * HW + sc0;
            int4 r0 = *(const int4*)xc;
            int4 r1 = *(const int4*)(xc + 8);
            u32* dst = (u32*)&Xs[skr * 130 + sc0];
#pragma unroll
            for (int i = 0; i < 4; i++) dst[i] = ((const u32*)&r0)[i];
#pragma unroll
            for (int i = 0; i < 4; i++) dst[4 + i] = ((const u32*)&r1)[i];
        }
        __syncthreads();
        bf16x8 af[4];
#pragma unroll
        for (int mi = 0; mi < 4; mi++) {
            int row = mi * 16 + l16;
            af[mi] = *(const bf16x8*)&Ws[(row << 5) + ((quad ^ (row & 3)) << 3)];
        }
#pragma unroll
        for (int ni = 0; ni < 2; ni++) {
            int n = wave * 32 + ni * 16 + l16;
            bf16x8 bfr;
#pragma unroll
            for (int j = 0; j < 8; j++) bfr[j] = (short)Xs[(quad * 8 + j) * 130 + n];
#pragma unroll
            for (int mi = 0; mi < 4; mi++)
                acc[mi][ni] = __builtin_amdgcn_mfma_f32_16x16x32_bf16(af[mi], bfr, acc[mi][ni], 0, 0, 0);
        }
    }
#pragma unroll
    for (int mi = 0; mi < 4; mi++) {
#pragma unroll
        for (int ni = 0; ni < 2; ni++) {
            int c0 = m0 + mi * 16 + quad * 4;
            int px = n0 + wave * 32 + ni * 16 + l16;
            ushort4 rv = *(const ushort4*)(residT + ((size_t)b * HW + px) * 192 + c0);
            float* ob = outp + ((size_t)b * 192 + c0) * HW + px;
            ob[0] = acc[mi][ni][0] + bf2f(rv.x);
            ob[(size_t)HW] = acc[mi][ni][1] + bf2f(rv.y);
            ob[(size_t)2 * HW] = acc[mi][ni][2] + bf2f(rv.z);
            ob[(size_t)3 * HW] = acc[mi][ni][3] + bf2f(rv.w);
        }
    }
}

// ---------------- K3: merged depthwise 3x3 (q + kv), float4 staging, sumsq ---
// One launch covers q (192 ch) and kv (384 ch) per batch; selects are
// block-uniform. sumsq partials: q all ch -> sqq; kv ch<192 (k-half) -> sqk.
__global__ __launch_bounds__(256) void k_dw2m(const u16* __restrict__ Xq,
                                              const u16* __restrict__ Xkv,
                                              const float* __restrict__ Wdq,
                                              const float* __restrict__ Wdkv,
                                              u16* __restrict__ outq,
                                              u16* __restrict__ outkv,
                                              float* __restrict__ sqq,
                                              float* __restrict__ sqk) {
    __shared__ float In[34 * 136];   // data cols at +4; borders at idx 3 / 132
    __shared__ float red[4];
    int bc = blockIdx.x >> 2, rt = blockIdx.x & 3;
    int b = bc / 576, ch = bc % 576;
    int isQ = (ch < 192);
    int c2 = isQ ? ch : ch - 192;
    const u16* xb = isQ ? Xq + ((size_t)(b * 192 + c2)) * HW
                        : Xkv + ((size_t)(b * 384 + c2)) * HW;
    const float* w = isQ ? (Wdq + c2 * 9) : (Wdkv + c2 * 9);
    u16* ob_base = isQ ? outq + ((size_t)(b * 192 + c2)) * HW
                       : outkv + ((size_t)(b * 384 + c2)) * HW;
    int t = threadIdx.x;
    int c0 = (t & 7) * 16;
    for (int r = t >> 3; r < 34; r += 32) {
        int y = rt * 32 - 1 + r;
        float* dst = &In[r * 136 + 4 + c0];
        if ((unsigned)y < 128u) {
            const u16* src = xb + y * 128 + c0;
            int4 r0 = *(const int4*)src;
            int4 r1 = *(const int4*)(src + 8);
            const u16* p0 = (const u16*)&r0;
            const u16* p1 = (const u16*)&r1;
            float4 f0 = {bf2f(p0[0]), bf2f(p0[1]), bf2f(p0[2]), bf2f(p0[3])};
            float4 f1 = {bf2f(p0[4]), bf2f(p0[5]), bf2f(p0[6]), bf2f(p0[7])};
            float4 f2 = {bf2f(p1[0]), bf2f(p1[1]), bf2f(p1[2]), bf2f(p1[3])};
            float4 f3 = {bf2f(p1[4]), bf2f(p1[5]), bf2f(p1[6]), bf2f(p1[7])};
            *(float4*)(dst) = f0;      *(float4*)(dst + 4) = f1;
            *(float4*)(dst + 8) = f2;  *(float4*)(dst + 12) = f3;
        } else {
            float4 z = {0.f, 0.f, 0.f, 0.f};
            *(float4*)(dst) = z;      *(float4*)(dst + 4) = z;
            *(float4*)(dst + 8) = z;  *(float4*)(dst + 12) = z;
        }
    }
    if (t < 34) { In[t * 136 + 3] = 0.f; In[t * 136 + 132] = 0.f; }
    __syncthreads();
    float w00 = w[0], w01 = w[1], w02 = w[2], w10 = w[3], w11 = w[4],
          w12 = w[5], w20 = w[6], w21 = w[7], w22 = w[8];
    int x = t & 127, rg = t >> 7;
    int base = rg * 16;
    float A2 = 0.f, A1 = 0.f, B1 = 0.f, ssq = 0.f;
    u16* ob = ob_base + (rt * 32 + base) * 128 + x;
#pragma unroll
    for (int r = 0; r < 18; r++) {
        const float* row = &In[(base + r) * 136 + 3 + x];
        float v0 = row[0], v1 = row[1], v2 = row[2];
        float h0 = w00 * v0 + w01 * v1 + w02 * v2;
        float h1 = w10 * v0 + w11 * v1 + w12 * v2;
        float h2 = w20 * v0 + w21 * v1 + w22 * v2;
        if (r >= 2) {
            float val = A2 + B1 + h2;
            ob[(size_t)(r - 2) * 128] = f2bf(val);
            ssq += val * val;
        }
        A2 = A1; A1 = h0; B1 = h1;
    }
    if (c2 < 192) {   // block-uniform (q: always; kv: k-half only)
        for (int o = 32; o > 0; o >>= 1) ssq += __shfl_down(ssq, o, 64);
        int wid = t >> 6, lane = t & 63;
        if (lane == 0) red[wid] = ssq;
        __syncthreads();
        float* sp = isQ ? sqq : sqk;
        if (t == 0) sp[((b * 192 + c2) << 2) | rt] = red[0] + red[1] + red[2] + red[3];
    }
}

// ---------------- K3b: depthwise 3x3 pair + exact GELU gate (float4 staging) -
__global__ __launch_bounds__(256) void k_dw_gelu2(const u16* __restrict__ G0,
                                                  const float* __restrict__ Wd,
                                                  u16* __restrict__ out) {
    __shared__ float In[2 * 34 * 136];
    int bc = blockIdx.x >> 2, rt = blockIdx.x & 3;
    int b = bc / 384, j = bc % 384;
    int t = threadIdx.x;
    int c0 = (t & 7) * 16;
    for (int pl = 0; pl < 2; pl++) {
        const u16* xb = G0 + ((size_t)b * 768 + pl * 384 + j) * HW;
        float* pla = &In[pl * 34 * 136];
        for (int r = t >> 3; r < 34; r += 32) {
            int y = rt * 32 - 1 + r;
            float* dst = &pla[r * 136 + 4 + c0];
            if ((unsigned)y < 128u) {
                const u16* src = xb + y * 128 + c0;
                int4 r0 = *(const int4*)src;
                int4 r1 = *(const int4*)(src + 8);
                const u16* p0 = (const u16*)&r0;
                const u16* p1 = (const u16*)&r1;
                float4 f0 = {bf2f(p0[0]), bf2f(p0[1]), bf2f(p0[2]), bf2f(p0[3])};
                float4 f1 = {bf2f(p0[4]), bf2f(p0[5]), bf2f(p0[6]), bf2f(p0[7])};
                float4 f2 = {bf2f(p1[0]), bf2f(p1[1]), bf2f(p1[2]), bf2f(p1[3])};
                float4 f3 = {bf2f(p1[4]), bf2f(p1[5]), bf2f(p1[6]), bf2f(p1[7])};
                *(float4*)(dst) = f0;      *(float4*)(dst + 4) = f1;
                *(float4*)(dst + 8) = f2;  *(float4*)(dst + 12) = f3;
            } else {
                float4 z = {0.f, 0.f, 0.f, 0.f};
                *(float4*)(dst) = z;      *(float4*)(dst + 4) = z;
                *(float4*)(dst + 8) = z;  *(float4*)(dst + 12) = z;
            }
        }
        if (t < 34) { pla[t * 136 + 3] = 0.f; pla[t * 136 + 132] = 0.f; }
    }
    __syncthreads();
    const float* w1 = Wd + j * 9;
    const float* w2 = Wd + (384 + j) * 9;
    float a00 = w1[0], a01 = w1[1], a02 = w1[2], a10 = w1[3], a11 = w1[4],
          a12 = w1[5], a20 = w1[6], a21 = w1[7], a22 = w1[8];
    float b00 = w2[0], b01 = w2[1], b02 = w2[2], b10 = w2[3], b11 = w2[4],
          b12 = w2[5], b20 = w2[6], b21 = w2[7], b22 = w2[8];
    int x = t & 127, rg = t >> 7;
    int base = rg * 16;
    float A2a = 0.f, A1a = 0.f, B1a = 0.f;
    float A2b = 0.f, A1b = 0.f, B1b = 0.f;
    u16* ob = out + ((size_t)b * 384 + j) * HW + (rt * 32 + base) * 128 + x;
#pragma unroll
    for (int r = 0; r < 18; r++) {
        const float* r1p = &In[(base + r) * 136 + 3 + x];
        const float* r2p = r1p + 34 * 136;
        float u0 = r1p[0], u1 = r1p[1], u2 = r1p[2];
        float v0 = r2p[0], v1 = r2p[1], v2 = r2p[2];
        float h0a = a00 * u0 + a01 * u1 + a02 * u2;
        float h1a = a10 * u0 + a11 * u1 + a12 * u2;
        float h2a = a20 * u0 + a21 * u1 + a22 * u2;
        float h0b = b00 * v0 + b01 * v1 + b02 * v2;
        float h1b = b10 * v0 + b11 * v1 + b12 * v2;
        float h2b = b20 * v0 + b21 * v1 + b22 * v2;
        if (r >= 2) {
            float s1 = A2a + B1a + h2a;
            float s2 = A2b + B1b + h2b;
            float g = 0.5f * s1 * (1.0f + erff(s1 * 0.70710678118654752f));
            ob[(size_t)(r - 2) * 128] = f2bf(g * s2);
        }
        A2a = A1a; A1a = h0a; B1a = h1a;
        A2b = A1b; A1b = h0b; B1b = h1b;
    }
}

// ---------------- K5: S partials = Q*K^T via MFMA, 64 d-chunks, prefetch -----
__global__ __launch_bounds__(256) void k_qk(const u16* __restrict__ qb_,
                                            const u16* __restrict__ kb_,
                                            float* __restrict__ Spart) {
    int bh = blockIdx.x >> 6, ds = blockIdx.x & 63;   // 768 blocks
    int b = bh / HEADS, h = bh % HEADS;
    int tid = threadIdx.x;
    int wave = tid >> 6, lane = tid & 63;
    int quad = lane >> 4, l16 = lane & 15;
    int tm = wave >> 1, tn = wave & 1;
    const u16* qrow = qb_ + ((size_t)(b * 192 + h * 32 + tm * 16 + l16)) * HW + ds * 256 + quad * 8;
    const u16* krow = kb_ + ((size_t)(b * 384 + h * 32 + tn * 16 + l16)) * HW + ds * 256 + quad * 8;
    f32x4 acc = {};
    bf16x8 qa[3], ka[3];
    auto ld = [&](int s, int cc) {
        qa[s] = *(const bf16x8*)(qrow + cc * 32);
        ka[s] = *(const bf16x8*)(krow + cc * 32);
    };
    ld(0, 0); ld(1, 1);
#pragma unroll
    for (int ch = 0; ch < 8; ch++) {
        if (ch + 2 < 8) ld((ch + 2) % 3, ch + 2);
        acc = __builtin_amdgcn_mfma_f32_16x16x32_bf16(qa[ch % 3], ka[ch % 3], acc, 0, 0, 0);
    }
    float* Sb = Spart + ((size_t)ds * 12 + bh) * 1024;
#pragma unroll
    for (int r = 0; r < 4; r++)
        Sb[(tm * 16 + quad * 4 + r) * 32 + tn * 16 + l16] = acc[r];
}

// ---------------- K6: reduce partials + normalize + softmax, bf16 out --------
__global__ void k_softmax(const float* __restrict__ Spart, const float* __restrict__ sqqp,
                          const float* __restrict__ sqkp, const float* __restrict__ temp,
                          u16* __restrict__ attnb) {
    int row = blockIdx.x;           // 0..383
    int bh = row >> 5, c2 = row & 31;
    int b = bh / HEADS, h = bh % HEADS;
    int e = threadIdx.x;            // 64 threads, active e<32
    float l = -1e30f;
    if (e < 32) {
        float s = 0.f;
        for (int d = 0; d < 64; d++) s += Spart[((size_t)d * 12 + bh) * 1024 + c2 * 32 + e];
        const float* qp = sqqp + (b * 192 + h * 32 + c2) * 4;
        const float* kp = sqkp + (b * 192 + h * 32 + e) * 4;
        float nq = qp[0] + qp[1] + qp[2] + qp[3];
        float nk = kp[0] + kp[1] + kp[2] + kp[3];
        float invq = 1.0f / fmaxf(sqrtf(nq), 1e-12f);
        float invk = 1.0f / fmaxf(sqrtf(nk), 1e-12f);
        l = s * invq * invk * temp[h];
    }
    float m = l;
    for (int o = 32; o > 0; o >>= 1) m = fmaxf(m, __shfl_xor(m, o, 64));
    float ev = (e < 32) ? expf(l - m) : 0.f;
    float ssum = ev;
    for (int o = 32; o > 0; o >>= 1) ssum += __shfl_xor(ssum, o, 64);
    if (e < 32) attnb[bh * 1024 + c2 * 32 + e] = f2bf(ev / ssum);
}

// ---------------- K7: out = attn @ V via MFMA, TRANSPOSED out [b][px][192] ---
__global__ __launch_bounds__(256) void k_av(const u16* __restrict__ attnb,
                                            const u16* __restrict__ kvb,
                                            u16* __restrict__ out) {
    __shared__ __align__(16) u16 Vs[32 * 130];
    int bh = blockIdx.x >> 7;       // 12
    int pt = blockIdx.x & 127;
    int b = bh / HEADS, h = bh % HEADS;
    int p0 = pt * 128;
    int t = threadIdx.x;
    {
        int e = t >> 3, c0 = (t & 7) * 16;
        const u16* src = kvb + ((size_t)(b * 384 + 192 + h * 32 + e)) * HW + p0 + c0;
        int4 r0 = *(const int4*)src;
        int4 r1 = *(const int4*)(src + 8);
        u32* dst = (u32*)&Vs[e * 130 + c0];
#pragma unroll
        for (int i = 0; i < 4; i++) dst[i] = ((const u32*)&r0)[i];
#pragma unroll
        for (int i = 0; i < 4; i++) dst[4 + i] = ((const u32*)&r1)[i];
    }
    __syncthreads();
    int wave = t >> 6, lane = t & 63;
    int quad = lane >> 4, l16 = lane & 15;
    f32x4 acc[2][2] = {};
    bf16x8 af[2];
#pragma unroll
    for (int tm = 0; tm < 2; tm++)
        af[tm] = *(const bf16x8*)(attnb + bh * 1024 + (tm * 16 + l16) * 32 + quad * 8);
#pragma unroll
    for (int nt = 0; nt < 2; nt++) {
        int n = wave * 32 + nt * 16 + l16;
        bf16x8 bfr;
#pragma unroll
        for (int j = 0; j < 8; j++) bfr[j] = (short)Vs[(quad * 8 + j) * 130 + n];
#pragma unroll
        for (int tm = 0; tm < 2; tm++)
            acc[tm][nt] = __builtin_amdgcn_mfma_f32_16x16x32_bf16(af[tm], bfr, acc[tm][nt], 0, 0, 0);
    }
#pragma unroll
    for (int tm = 0; tm < 2; tm++)
#pragma unroll
        for (int nt = 0; nt < 2; nt++) {
            int c0 = h * 32 + tm * 16 + quad * 4;
            int px = p0 + wave * 32 + nt * 16 + l16;
            ushort4 o;
            o.x = f2bf(acc[tm][nt][0]);
            o.y = f2bf(acc[tm][nt][1]);
            o.z = f2bf(acc[tm][nt][2]);
            o.w = f2bf(acc[tm][nt][3]);
            *(ushort4*)(out + ((size_t)b * HW + px) * 192 + c0) = o;
        }
}

extern "C" void kernel_launch(void* const* d_in, const int* in_sizes, int n_in,
                              void* d_out, int out_size, void* d_ws, size_t ws_size,
                              hipStream_t stream) {
    const float* x     = (const float*)d_in[0];
    const float* k_v   = (const float*)d_in[1];
    const float* ln1w  = (const float*)d_in[2];
    const float* ln1b  = (const float*)d_in[3];
    const float* temp  = (const float*)d_in[4];
    const float* w_kR  = (const float*)d_in[5];
    const float* w_kI  = (const float*)d_in[6];
    const float* w_qR  = (const float*)d_in[7];
    const float* w_qdw = (const float*)d_in[8];
    const float* w_kvI = (const float*)d_in[9];
    const float* w_kvdw= (const float*)d_in[10];
    const float* w_po  = (const float*)d_in[11];
    const float* ln2w  = (const float*)d_in[12];
    const float* ln2b  = (const float*)d_in[13];
    const float* w_ffk = (const float*)d_in[14];
    const float* w_pin = (const float*)d_in[15];
    const float* w_dw  = (const float*)d_in[16];
    const float* w_pout= (const float*)d_in[17];
    float* out = (float*)d_out;

    const size_t MiB = 1048576ULL;
    // Region plan (disjoint lifetimes; peak ~150 MiB):
    u16*   q0b     = wsh(d_ws, 0);          // [2][192][HW] std; reused: Spart, attnoutT, y0T
    u16*   attnoutb= wsh(d_ws, 0);          // [2][HW][192] T
    u16*   y0b     = wsh(d_ws, 0);          // [2][HW][192] T (k_gemm_po: same-block alias, safe)
    u16*   kv0b    = wsh(d_ws, 12 * MiB);   // [2][384][HW] std; reused: ybuf
    u16*   ybufb   = wsh(d_ws, 12 * MiB);
    u16*   x1b     = wsh(d_ws, 36 * MiB);   // [2][HW][192] T (po->pout resid)
    u16*   qbuf_b  = wsh(d_ws, 48 * MiB);   // [2][192][HW] std (dwq->qk)
    u16*   kvbuf_b = wsh(d_ws, 60 * MiB);   // [2][384][HW] std (dwkv->qk/av)
    u16*   xrb     = wsh(d_ws, 84 * MiB);   // [2][HW][160] T (exact 10 MiB)
    u16*   xib     = wsh(d_ws, 94 * MiB);   // [2][HW][64]  T (exact 4 MiB)
    u16*   g0b     = wsh(d_ws, 98 * MiB);   // [2][768][HW] std (pin->gelu)
    u16*   wb      = wsh(d_ws, 146 * MiB);  // bf16 weights, 627 KB
    float* sm      = wsf(d_ws, 147 * MiB);  // smalls
    float* Spart   = wsf(d_ws, 0);          // 64*12*1024 fp32 = 3 MiB over dead q0b
    u16* wq   = wb;            // [192][160]
    u16* wkv  = wb + 30720;    // [384][64]
    u16* wpo  = wb + 55296;    // [192][192]
    u16* wpin = wb + 92160;    // [768][192]
    u16* wpout= wb + 239616;   // [192][384]
    float* kvr  = sm;               // 288
    float* kvi  = sm + 288;         // 96
    // kvf = sm + 384 (written, unused directly)
    float* sqqp = sm + 768;         // 1536 (4 row-tile partials x 384 rows)
    float* sqkp = sm + 2304;        // 1536
    u16*   attnb= (u16*)(sm + 3840);// 12288 bf16 (ends at float 9984)
    float* A2c  = sm + 10240;       // 384 (ln2w * (kvf+1))
    float* B2c  = sm + 10624;       // 384 (ln2b * (kvf+1))

    k_setup<<<1229, 256, 0, stream>>>(k_v, w_kR, w_kI, w_ffk, w_qR, w_kvI, w_po,
                                      w_pin, w_pout, ln2w, ln2b, wb, sm, A2c, B2c,
                                      out + (size_t)NB * CDIM * HW);
    k_ln1<<<NPX / 64, 256, 0, stream>>>(x, ln1w, ln1b, kvr, kvi, xrb, xib);
    k_gemm_t<5, 0><<<dim3(128, 3, 2), 256, 0, stream>>>(xrb, wq, nullptr, q0b, 192);
    k_gemm_t<2, 0><<<dim3(128, 6, 2), 256, 0, stream>>>(xib, wkv, nullptr, kv0b, 384);
    k_dw2m<<<NB * 576 * 4, 256, 0, stream>>>(q0b, kv0b, w_qdw, w_kvdw,
                                             qbuf_b, kvbuf_b, sqqp, sqkp);
    k_qk<<<12 * 64, 256, 0, stream>>>(qbuf_b, kvbuf_b, Spart);
    k_softmax<<<384, 64, 0, stream>>>(Spart, sqqp, sqkp, temp, attnb);
    k_av<<<12 * 128, 256, 0, stream>>>(attnb, kvbuf_b, attnoutb);
    k_gemm_po<<<dim3(256, 2), 256, 0, stream>>>(attnoutb, wpo, x, A2c, B2c, x1b, y0b);
    k_gemm_t<6, 0><<<dim3(128, 12, 2), 256, 0, stream>>>(y0b, wpin, nullptr, g0b, 768);
    k_dw_gelu2<<<NB * 384 * 4, 256, 0, stream>>>(g0b, w_dw, ybufb);
    k_gemm_s<<<dim3(128, 3, 2), 256, 0, stream>>>(ybufb, wpout, x1b, out);
}